// Round 2
// baseline (1367.598 us; speedup 1.0000x reference)
//
#include <hip/hip_runtime.h>

// LSTM T=1024, B=2048, INPUT=2, H=64 — fully fused, batch-parallel fp32.
// R1: 4 batch/block (512 blocks, 2/CU), __launch_bounds__(256,2) so the
// 64-VGPR W_hh row array stays in registers (R0's VGPR=52 proved eviction),
// v_rcp-based activations (no fp32 div sequence), x chunked through LDS,
// c-update spread across all 256 threads.

constexpr int T_STEPS = 1024;
constexpr int BATCH   = 2048;
constexpr int H       = 64;
constexpr int CHUNK   = 128;                 // x timesteps staged per LDS refill
constexpr int NCHUNK  = T_STEPS / CHUNK;     // 8

__device__ __forceinline__ float fast_rcp(float x)  { return __builtin_amdgcn_rcpf(x); }
__device__ __forceinline__ float fast_exp2(float x) { return __builtin_amdgcn_exp2f(x); }

// sigmoid(v) = 1/(1+2^(-v*log2e))
__device__ __forceinline__ float fast_sigmoid(float v) {
    return fast_rcp(1.0f + fast_exp2(v * -1.44269504f));
}
// tanh(v) = 1 - 2/(1+2^(2v*log2e))
__device__ __forceinline__ float fast_tanh(float v) {
    return fmaf(-2.0f, fast_rcp(1.0f + fast_exp2(v * 2.88539008f)), 1.0f);
}

__global__ __launch_bounds__(256, 2) void lstm_fused4(
    const float* __restrict__ x,      // (T, B, 2)
    const float* __restrict__ W_ih,   // (256, 2)
    const float* __restrict__ W_hh,   // (256, 64)
    const float* __restrict__ b_ih,   // (256)
    const float* __restrict__ b_hh,   // (256)
    const float* __restrict__ W_fc,   // (1, 64)
    const float* __restrict__ b_fc,   // (1)
    float* __restrict__ out)          // (B, 1)
{
    const int t  = threadIdx.x;       // gate row 0..255
    const int b0 = blockIdx.x * 4;    // four batch elements per block

    __shared__ __align__(16) float sh[4][H];      // hidden state per batch elem
    __shared__ __align__(16) float sact[4][256];  // activated gates
    __shared__ __align__(16) float sx[CHUNK * 8]; // x chunk: [step][8 floats]

    // --- per-thread constants ---------------------------------------------
    float4 w4[16];
    const float4* wrow = reinterpret_cast<const float4*>(W_hh + t * H);
    #pragma unroll
    for (int k = 0; k < 16; ++k) w4[k] = wrow[k];

    const float wx0  = W_ih[t * 2 + 0];
    const float wx1  = W_ih[t * 2 + 1];
    const float bias = b_ih[t] + b_hh[t];
    const int   gate = t >> 6;        // 0:i 1:f 2:g 3:o (wave-uniform)

    // c-state for (batch t>>6, h-index t&63) lives in this thread
    float c = 0.0f;
    sh[t >> 6][t & 63] = 0.0f;

    // --- x chunk prefetch (1 float4 per thread) ---------------------------
    // float4 #t of a chunk = step (t>>1), half (t&1) of the 8 floats b0..b0+3
    const float* xb = x + b0 * 2;
    const int pf_step = t >> 1;
    const int pf_part = t & 1;
    float4 pf = reinterpret_cast<const float4*>(xb + pf_step * (BATCH * 2))[pf_part];

    for (int chunk = 0; chunk < NCHUNK; ++chunk) {
        // previous chunk fully consumed (end-of-step barrier), safe to overwrite
        reinterpret_cast<float4*>(sx)[t] = pf;
        __syncthreads();
        if (chunk + 1 < NCHUNK) {
            pf = reinterpret_cast<const float4*>(
                     xb + ((chunk + 1) * CHUNK + pf_step) * (BATCH * 2))[pf_part];
        }

        for (int s = 0; s < CHUNK; ++s) {
            const float4 xa = reinterpret_cast<const float4*>(sx + s * 8)[0];
            const float4 xc = reinterpret_cast<const float4*>(sx + s * 8)[1];

            float acc0 = fmaf(wx1, xa.y, fmaf(wx0, xa.x, bias));
            float acc1 = fmaf(wx1, xa.w, fmaf(wx0, xa.z, bias));
            float acc2 = fmaf(wx1, xc.y, fmaf(wx0, xc.x, bias));
            float acc3 = fmaf(wx1, xc.w, fmaf(wx0, xc.z, bias));

            const float4* h0 = reinterpret_cast<const float4*>(sh[0]);
            const float4* h1 = reinterpret_cast<const float4*>(sh[1]);
            const float4* h2 = reinterpret_cast<const float4*>(sh[2]);
            const float4* h3 = reinterpret_cast<const float4*>(sh[3]);
            #pragma unroll
            for (int k = 0; k < 16; ++k) {
                const float4 w  = w4[k];
                const float4 a0 = h0[k];
                const float4 a1 = h1[k];
                const float4 a2 = h2[k];
                const float4 a3 = h3[k];
                acc0 = fmaf(w.x, a0.x, acc0); acc0 = fmaf(w.y, a0.y, acc0);
                acc0 = fmaf(w.z, a0.z, acc0); acc0 = fmaf(w.w, a0.w, acc0);
                acc1 = fmaf(w.x, a1.x, acc1); acc1 = fmaf(w.y, a1.y, acc1);
                acc1 = fmaf(w.z, a1.z, acc1); acc1 = fmaf(w.w, a1.w, acc1);
                acc2 = fmaf(w.x, a2.x, acc2); acc2 = fmaf(w.y, a2.y, acc2);
                acc2 = fmaf(w.z, a2.z, acc2); acc2 = fmaf(w.w, a2.w, acc2);
                acc3 = fmaf(w.x, a3.x, acc3); acc3 = fmaf(w.y, a3.y, acc3);
                acc3 = fmaf(w.z, a3.z, acc3); acc3 = fmaf(w.w, a3.w, acc3);
            }

            float a0, a1, a2, a3;
            if (gate == 2) {            // wave-uniform branch
                a0 = fast_tanh(acc0); a1 = fast_tanh(acc1);
                a2 = fast_tanh(acc2); a3 = fast_tanh(acc3);
            } else {
                a0 = fast_sigmoid(acc0); a1 = fast_sigmoid(acc1);
                a2 = fast_sigmoid(acc2); a3 = fast_sigmoid(acc3);
            }
            sact[0][t] = a0;
            sact[1][t] = a1;
            sact[2][t] = a2;
            sact[3][t] = a3;
            __syncthreads();

            // c/h update: every thread owns one (batch, h-index) pair
            {
                const int b  = t >> 6;
                const int hh = t & 63;
                const float iv = sact[b][hh];
                const float fv = sact[b][H + hh];
                const float gv = sact[b][2 * H + hh];
                const float ov = sact[b][3 * H + hh];
                c = fmaf(fv, c, iv * gv);
                sh[b][hh] = ov * fast_tanh(c);
            }
            __syncthreads();
        }
    }

    // --- fused fc epilogue: wave w reduces batch w ------------------------
    {
        const int w    = t >> 6;
        const int lane = t & 63;
        float v = sh[w][lane] * W_fc[lane];
        #pragma unroll
        for (int off = 32; off; off >>= 1) v += __shfl_down(v, off);
        if (lane == 0) out[b0 + w] = v + b_fc[0];
    }
}

extern "C" void kernel_launch(void* const* d_in, const int* in_sizes, int n_in,
                              void* d_out, int out_size, void* d_ws, size_t ws_size,
                              hipStream_t stream) {
    const float* x    = (const float*)d_in[0];
    const float* W_ih = (const float*)d_in[1];
    const float* W_hh = (const float*)d_in[2];
    const float* b_ih = (const float*)d_in[3];
    const float* b_hh = (const float*)d_in[4];
    const float* W_fc = (const float*)d_in[5];
    const float* b_fc = (const float*)d_in[6];
    float* out = (float*)d_out;

    dim3 grid(BATCH / 4);   // 512 blocks, 4 batch elements each
    dim3 block(256);
    lstm_fused4<<<grid, block, 0, stream>>>(x, W_ih, W_hh, b_ih, b_hh, W_fc, b_fc, out);
}

// Round 3
// 775.213 us; speedup vs baseline: 1.7642x; 1.7642x over previous
//
#include <hip/hip_runtime.h>

// LSTM T=1024, B=2048, INPUT=2, H=64 — MFMA recurrence.
// gates^T = W_hh(256x64) . h^T(64x16) per step, mfma_f32_16x16x32_bf16.
// 128 blocks x 512 threads (8 waves). Wave w owns gate rows 32w..32w+31
// (2 M-tiles); gate type = w>>1 (uniform activation). W_hh split hi+lo bf16
// (hoisted in regs); h quantized to bf16 each step (fresh rounding, fp32 c).

typedef short  bf16x8 __attribute__((ext_vector_type(8)));
typedef float  f32x4  __attribute__((ext_vector_type(4)));

constexpr int T_STEPS = 1024;
constexpr int BATCH   = 2048;
constexpr int H       = 64;
constexpr int BB      = 16;            // batch columns per block
constexpr int THREADS = 512;           // 8 waves
constexpr int CHUNK   = 128;           // x timesteps per LDS stage
constexpr int NCHUNK  = T_STEPS / CHUNK;
constexpr int ACT_STRIDE = 260;        // f32 per batch col (256 rows + pad)
constexpr int HT_STRIDE  = 72;         // bf16 per batch col (64 + pad)

__device__ __forceinline__ unsigned short bf16_rn(float f) {
    unsigned u = __float_as_uint(f);
    u += 0x7fffu + ((u >> 16) & 1u);
    return (unsigned short)(u >> 16);
}
__device__ __forceinline__ float bf16_f(unsigned short h) {
    return __uint_as_float(((unsigned)h) << 16);
}
__device__ __forceinline__ float sigm(float v) {
    return __builtin_amdgcn_rcpf(1.0f + __builtin_amdgcn_exp2f(v * -1.44269504f));
}
__device__ __forceinline__ float tanh_(float v) {
    return fmaf(-2.0f, __builtin_amdgcn_rcpf(1.0f + __builtin_amdgcn_exp2f(v * 2.88539008f)), 1.0f);
}

__global__ __launch_bounds__(THREADS, 2) void lstm_mfma(
    const float* __restrict__ x,      // (T, B, 2)
    const float* __restrict__ W_ih,   // (256, 2)
    const float* __restrict__ W_hh,   // (256, 64)
    const float* __restrict__ b_ih,   // (256)
    const float* __restrict__ b_hh,   // (256)
    const float* __restrict__ W_fc,   // (1, 64)
    const float* __restrict__ b_fc,   // (1)
    float* __restrict__ out)          // (B, 1)
{
    const int tid  = threadIdx.x;
    const int w    = tid >> 6;        // wave 0..7
    const int lane = tid & 63;
    const int bcol = lane & 15;       // MFMA n / A-row lane index
    const int grp  = lane >> 4;       // k-group 0..3

    __shared__ __align__(16) float          s_act[BB * ACT_STRIDE]; // 16.6 KB
    __shared__ __align__(16) unsigned short s_ht [BB * HT_STRIDE];  // 2.3 KB
    __shared__ __align__(16) float          s_x  [CHUNK * 2 * BB];  // 16 KB
    __shared__ __align__(16) float          s_red[THREADS];         // 2 KB

    const int b0 = blockIdx.x * BB;

    // ---- hoisted A fragments: W_hh rows, hi/lo bf16 split ----------------
    // A[mt][kk]: lane holds W[(2w+mt)*16 + bcol][kk*32 + grp*8 + j], j=0..7
    bf16x8 Ahi[2][2], Alo[2][2];
    #pragma unroll
    for (int mt = 0; mt < 2; ++mt) {
        const int row = (2 * w + mt) * 16 + bcol;
        #pragma unroll
        for (int kk = 0; kk < 2; ++kk) {
            const float* src = W_hh + row * H + kk * 32 + grp * 8;
            #pragma unroll
            for (int j = 0; j < 8; ++j) {
                const float v = src[j];
                const unsigned short hi = bf16_rn(v);
                const unsigned short lo = bf16_rn(v - bf16_f(hi));
                Ahi[mt][kk][j] = (short)hi;
                Alo[mt][kk][j] = (short)lo;
            }
        }
    }

    // ---- hoisted gx constants: D rows this lane owns ---------------------
    // D row = (2w+mt)*16 + grp*4 + e, col = bcol
    float bias_[2][4], wx0_[2][4], wx1_[2][4];
    #pragma unroll
    for (int mt = 0; mt < 2; ++mt)
        #pragma unroll
        for (int e = 0; e < 4; ++e) {
            const int r = 32 * w + 16 * mt + 4 * grp + e;
            bias_[mt][e] = b_ih[r] + b_hh[r];
            wx0_[mt][e]  = W_ih[2 * r];
            wx1_[mt][e]  = W_ih[2 * r + 1];
        }

    // ---- c/h ownership: thread -> (batch bo, h pair 2*h2, 2*h2+1) --------
    const int bo = tid & 15;
    const int h2 = tid >> 4;          // 0..31
    float c0 = 0.0f, c1 = 0.0f, hf0 = 0.0f, hf1 = 0.0f;
    const float wfc0 = W_fc[2 * h2];
    const float wfc1 = W_fc[2 * h2 + 1];

    // ---- x staging helpers ----------------------------------------------
    auto xld = [&](int chunk, int idx) -> float4 {
        const int sl = idx >> 3, j = idx & 7;   // step-in-chunk, 4-float group
        return *reinterpret_cast<const float4*>(
            x + ((chunk * CHUNK + sl) * BATCH + b0) * 2 + j * 4);
    };
    auto xst = [&](float4 a, float4 b) {
        const int sl = tid >> 3, j = tid & 7;
        *reinterpret_cast<float4*>(&s_x[sl * 32 + j * 4])        = a;
        *reinterpret_cast<float4*>(&s_x[(sl + 64) * 32 + j * 4]) = b;
    };

    // stage chunk 0; zero h-table
    xst(xld(0, tid), xld(0, tid + THREADS));
    for (int i = tid; i < BB * HT_STRIDE; i += THREADS) s_ht[i] = 0;
    __syncthreads();

    float4 pf0 = xld(1, tid), pf1 = xld(1, tid + THREADS);  // prefetch chunk 1

    // initial B fragments (h = 0)
    bf16x8 Bf[2];
    #pragma unroll
    for (int kk = 0; kk < 2; ++kk)
        Bf[kk] = *reinterpret_cast<const bf16x8*>(
                     &s_ht[bcol * HT_STRIDE + kk * 32 + grp * 8]);

    for (int s = 0; s < T_STEPS; ++s) {
        const int sl = s & (CHUNK - 1);
        const float2 xv = *reinterpret_cast<const float2*>(&s_x[sl * 32 + 2 * bcol]);

        // acc init = bias + W_ih . x  (exact fp32)
        f32x4 acc[2];
        #pragma unroll
        for (int mt = 0; mt < 2; ++mt)
            #pragma unroll
            for (int e = 0; e < 4; ++e)
                acc[mt][e] = fmaf(wx1_[mt][e], xv.y,
                              fmaf(wx0_[mt][e], xv.x, bias_[mt][e]));

        // recurrent GEMM: 2 tiles x 2 k-steps x (hi+lo)
        #pragma unroll
        for (int mt = 0; mt < 2; ++mt)
            #pragma unroll
            for (int kk = 0; kk < 2; ++kk) {
                acc[mt] = __builtin_amdgcn_mfma_f32_16x16x32_bf16(
                              Ahi[mt][kk], Bf[kk], acc[mt], 0, 0, 0);
                acc[mt] = __builtin_amdgcn_mfma_f32_16x16x32_bf16(
                              Alo[mt][kk], Bf[kk], acc[mt], 0, 0, 0);
            }

        // activation (wave-uniform gate type) + write to LDS
        const int gate = w >> 1;
        #pragma unroll
        for (int mt = 0; mt < 2; ++mt) {
            float4 av;
            if (gate == 2) {
                av.x = tanh_(acc[mt][0]); av.y = tanh_(acc[mt][1]);
                av.z = tanh_(acc[mt][2]); av.w = tanh_(acc[mt][3]);
            } else {
                av.x = sigm(acc[mt][0]); av.y = sigm(acc[mt][1]);
                av.z = sigm(acc[mt][2]); av.w = sigm(acc[mt][3]);
            }
            *reinterpret_cast<float4*>(
                &s_act[bcol * ACT_STRIDE + 32 * w + 16 * mt + 4 * grp]) = av;
        }
        __syncthreads();   // bar1: act visible; prior-step B-frag reads done

        // c/h update: 2 (b,h) pairs per thread, all in fp32
        {
            const float* ab = &s_act[bo * ACT_STRIDE + 2 * h2];
            const float2 iv = *reinterpret_cast<const float2*>(ab);
            const float2 fv = *reinterpret_cast<const float2*>(ab + 64);
            const float2 gv = *reinterpret_cast<const float2*>(ab + 128);
            const float2 ov = *reinterpret_cast<const float2*>(ab + 192);
            c0 = fmaf(fv.x, c0, iv.x * gv.x);
            c1 = fmaf(fv.y, c1, iv.y * gv.y);
            hf0 = ov.x * tanh_(c0);
            hf1 = ov.y * tanh_(c1);
            const unsigned pack = (unsigned)bf16_rn(hf0)
                                | ((unsigned)bf16_rn(hf1) << 16);
            *reinterpret_cast<unsigned*>(&s_ht[bo * HT_STRIDE + 2 * h2]) = pack;
        }

        // x chunk refill (writes between bar1/bar2; readers resume after bar2)
        if (sl == CHUNK - 1 && s + 1 < T_STEPS) {
            xst(pf0, pf1);
            const int nc = (s >> 7) + 2;
            if (nc < NCHUNK) { pf0 = xld(nc, tid); pf1 = xld(nc, tid + THREADS); }
        }
        __syncthreads();   // bar2: h-table + x stage visible

        #pragma unroll
        for (int kk = 0; kk < 2; ++kk)
            Bf[kk] = *reinterpret_cast<const bf16x8*>(
                         &s_ht[bcol * HT_STRIDE + kk * 32 + grp * 8]);
    }

    // ---- fused fc epilogue ----------------------------------------------
    s_red[tid] = fmaf(hf0, wfc0, hf1 * wfc1);
    __syncthreads();
    if (tid < BB) {
        float acc = b_fc[0];
        #pragma unroll
        for (int k = 0; k < 32; ++k) acc += s_red[tid + 16 * k];
        out[b0 + tid] = acc;
    }
}

extern "C" void kernel_launch(void* const* d_in, const int* in_sizes, int n_in,
                              void* d_out, int out_size, void* d_ws, size_t ws_size,
                              hipStream_t stream) {
    const float* x    = (const float*)d_in[0];
    const float* W_ih = (const float*)d_in[1];
    const float* W_hh = (const float*)d_in[2];
    const float* b_ih = (const float*)d_in[3];
    const float* b_hh = (const float*)d_in[4];
    const float* W_fc = (const float*)d_in[5];
    const float* b_fc = (const float*)d_in[6];
    float* out = (float*)d_out;

    dim3 grid(BATCH / BB);   // 128 blocks
    dim3 block(THREADS);     // 8 waves
    lstm_mfma<<<grid, block, 0, stream>>>(x, W_ih, W_hh, b_ih, b_hh, W_fc, b_fc, out);
}

// Round 4
// 553.053 us; speedup vs baseline: 2.4728x; 1.4017x over previous
//
#include <hip/hip_runtime.h>

// LSTM T=1024, B=2048, INPUT=2, H=64 — MFMA recurrence, latency-optimized.
// R3: 4 waves/block; wave w owns h-rows [16w,16w+16) and computes ALL FOUR
// gate tiles for that slice -> i,f,g,o of each (h,batch) land in one lane's
// registers (D: col=lane&15, row=4*(lane>>4)+e). c/h update fully in-register.
// Single LDS round-trip per step (h-table, double-buffered, ONE barrier).
// x via depth-2 register prefetch from global. Numerics = R2 (bf16 hi/lo W).

typedef short bf16x4 __attribute__((ext_vector_type(4)));
typedef short bf16x8 __attribute__((ext_vector_type(8)));
typedef float f32x4  __attribute__((ext_vector_type(4)));

constexpr int T_STEPS = 1024;
constexpr int BATCH   = 2048;
constexpr int H       = 64;
constexpr int BB      = 16;     // batch per block
constexpr int THREADS = 256;    // 4 waves
constexpr int HSTR    = 68;     // bf16 per batch row: 64 + 4 pad (34 dwords)

__device__ __forceinline__ unsigned bf16_rn(float f) {
    unsigned u = __float_as_uint(f);
    u += 0x7fffu + ((u >> 16) & 1u);
    return u >> 16;
}
__device__ __forceinline__ float bf16_f(unsigned h) {
    return __uint_as_float(h << 16);
}
__device__ __forceinline__ float sigm(float v) {
    return __builtin_amdgcn_rcpf(1.0f + __builtin_amdgcn_exp2f(v * -1.44269504f));
}
__device__ __forceinline__ float tanh_(float v) {
    return fmaf(-2.0f, __builtin_amdgcn_rcpf(1.0f + __builtin_amdgcn_exp2f(v * 2.88539008f)), 1.0f);
}

__global__ __launch_bounds__(THREADS, 1) void lstm_mfma4(
    const float* __restrict__ x,      // (T, B, 2)
    const float* __restrict__ W_ih,   // (256, 2)
    const float* __restrict__ W_hh,   // (256, 64)
    const float* __restrict__ b_ih,   // (256)
    const float* __restrict__ b_hh,   // (256)
    const float* __restrict__ W_fc,   // (1, 64)
    const float* __restrict__ b_fc,   // (1)
    float* __restrict__ out)          // (B, 1)
{
    const int tid  = threadIdx.x;
    const int w    = tid >> 6;        // wave 0..3: h-slice [16w, 16w+16)
    const int lane = tid & 63;
    const int bcol = lane & 15;       // batch column
    const int grp  = lane >> 4;       // k-group / D-row group

    __shared__ __align__(16) unsigned short s_ht[2][BB * HSTR]; // 2x2176 B
    __shared__ float s_red[64];

    const int b0 = blockIdx.x * BB;

    // ---- A fragments: gate g tile = W_hh rows [64g+16w, +16) -------------
    // lane holds A[row=bcol][k=grp*8+j] (+32*kk), hi/lo bf16 split
    bf16x8 Ahi[4][2], Alo[4][2];
    #pragma unroll
    for (int g = 0; g < 4; ++g) {
        #pragma unroll
        for (int kk = 0; kk < 2; ++kk) {
            const float* src = W_hh + (64 * g + 16 * w + bcol) * H + kk * 32 + grp * 8;
            #pragma unroll
            for (int j = 0; j < 8; ++j) {
                const float v = src[j];
                const unsigned hi = bf16_rn(v);
                const unsigned lo = bf16_rn(v - bf16_f(hi));
                Ahi[g][kk][j] = (short)hi;
                Alo[g][kk][j] = (short)lo;
            }
        }
    }

    // ---- gx constants: D row (gate g) = 64g + 16w + 4grp + e -------------
    float gb[4][4], c0[4][4], c1[4][4];
    #pragma unroll
    for (int g = 0; g < 4; ++g)
        #pragma unroll
        for (int e = 0; e < 4; ++e) {
            const int r = 64 * g + 16 * w + 4 * grp + e;
            gb[g][e] = b_ih[r] + b_hh[r];
            c0[g][e] = W_ih[2 * r];
            c1[g][e] = W_ih[2 * r + 1];
        }

    // ---- per-lane state: (h-index 16w+4grp+e, batch bcol), e=0..3 --------
    float cst[4] = {0.f, 0.f, 0.f, 0.f};
    float hv[4]  = {0.f, 0.f, 0.f, 0.f};
    const float4 wfc = *reinterpret_cast<const float4*>(W_fc + 16 * w + 4 * grp);

    // zero h-table buf 0 (and 1)
    for (int i = tid; i < 2 * BB * HSTR / 2; i += THREADS)
        reinterpret_cast<unsigned*>(s_ht)[i] = 0;

    // ---- x: depth-2 register prefetch ------------------------------------
    const float* xb = x + (b0 + bcol) * 2;
    float2 xc  = *reinterpret_cast<const float2*>(xb);
    float2 xn1 = *reinterpret_cast<const float2*>(xb + 1 * BATCH * 2);
    float2 xn2 = *reinterpret_cast<const float2*>(xb + 2 * BATCH * 2);

    __syncthreads();

    // initial B fragments from buf 0 (h = 0)
    bf16x8 Bf[2];
    {
        const unsigned short* hb = &s_ht[0][bcol * HSTR];
        #pragma unroll
        for (int kk = 0; kk < 2; ++kk) {
            bf16x4 lo4 = *reinterpret_cast<const bf16x4*>(hb + kk * 32 + grp * 8);
            bf16x4 hi4 = *reinterpret_cast<const bf16x4*>(hb + kk * 32 + grp * 8 + 4);
            Bf[kk] = __builtin_shufflevector(lo4, hi4, 0, 1, 2, 3, 4, 5, 6, 7);
        }
    }

    #pragma unroll 2
    for (int s = 0; s < T_STEPS; ++s) {
        // acc init = gx (exact fp32)
        f32x4 acc[4];
        #pragma unroll
        for (int g = 0; g < 4; ++g)
            #pragma unroll
            for (int e = 0; e < 4; ++e)
                acc[g][e] = fmaf(c1[g][e], xc.y, fmaf(c0[g][e], xc.x, gb[g][e]));

        // recurrent GEMM: 4 independent gate-chains of 4 dependent MFMAs
        #pragma unroll
        for (int kk = 0; kk < 2; ++kk) {
            #pragma unroll
            for (int g = 0; g < 4; ++g)
                acc[g] = __builtin_amdgcn_mfma_f32_16x16x32_bf16(Ahi[g][kk], Bf[kk], acc[g], 0, 0, 0);
            #pragma unroll
            for (int g = 0; g < 4; ++g)
                acc[g] = __builtin_amdgcn_mfma_f32_16x16x32_bf16(Alo[g][kk], Bf[kk], acc[g], 0, 0, 0);
        }

        // activations + c/h update, fully in-register
        #pragma unroll
        for (int e = 0; e < 4; ++e) {
            const float iv = sigm(acc[0][e]);
            const float fv = sigm(acc[1][e]);
            const float gv = tanh_(acc[2][e]);
            const float ov = sigm(acc[3][e]);
            cst[e] = fmaf(fv, cst[e], iv * gv);
            hv[e]  = ov * tanh_(cst[e]);
        }

        // pack h -> bf16, write to next-parity h-table
        {
            const unsigned p0 = bf16_rn(hv[0]) | (bf16_rn(hv[1]) << 16);
            const unsigned p1 = bf16_rn(hv[2]) | (bf16_rn(hv[3]) << 16);
            uint2* dst = reinterpret_cast<uint2*>(
                &s_ht[(s + 1) & 1][bcol * HSTR + 16 * w + 4 * grp]);
            *dst = make_uint2(p0, p1);
        }

        // rotate x prefetch (depth 2)
        xc = xn1; xn1 = xn2;
        const int sn = (s + 3 < T_STEPS) ? s + 3 : T_STEPS - 1;
        xn2 = *reinterpret_cast<const float2*>(xb + sn * BATCH * 2);

        __syncthreads();   // h-table (next parity) visible

        // B fragments for next step (two 8B-aligned b64 reads per kk)
        {
            const unsigned short* hb = &s_ht[(s + 1) & 1][bcol * HSTR];
            #pragma unroll
            for (int kk = 0; kk < 2; ++kk) {
                bf16x4 lo4 = *reinterpret_cast<const bf16x4*>(hb + kk * 32 + grp * 8);
                bf16x4 hi4 = *reinterpret_cast<const bf16x4*>(hb + kk * 32 + grp * 8 + 4);
                Bf[kk] = __builtin_shufflevector(lo4, hi4, 0, 1, 2, 3, 4, 5, 6, 7);
            }
        }
    }

    // ---- fused fc epilogue ----------------------------------------------
    float v = fmaf(hv[0], wfc.x, fmaf(hv[1], wfc.y,
              fmaf(hv[2], wfc.z, hv[3] * wfc.w)));
    v += __shfl_xor(v, 16);
    v += __shfl_xor(v, 32);          // all grp summed; lane holds total for bcol
    if (lane < 16) s_red[w * 16 + lane] = v;
    __syncthreads();
    if (tid < 16) {
        out[b0 + tid] = s_red[tid] + s_red[16 + tid] + s_red[32 + tid]
                      + s_red[48 + tid] + b_fc[0];
    }
}

extern "C" void kernel_launch(void* const* d_in, const int* in_sizes, int n_in,
                              void* d_out, int out_size, void* d_ws, size_t ws_size,
                              hipStream_t stream) {
    const float* x    = (const float*)d_in[0];
    const float* W_ih = (const float*)d_in[1];
    const float* W_hh = (const float*)d_in[2];
    const float* b_ih = (const float*)d_in[3];
    const float* b_hh = (const float*)d_in[4];
    const float* W_fc = (const float*)d_in[5];
    const float* b_fc = (const float*)d_in[6];
    float* out = (float*)d_out;

    dim3 grid(BATCH / BB);   // 128 blocks
    dim3 block(THREADS);     // 4 waves
    lstm_mfma4<<<grid, block, 0, stream>>>(x, W_ih, W_hh, b_ih, b_hh, W_fc, b_fc, out);
}

// Round 5
// 466.554 us; speedup vs baseline: 2.9313x; 1.1854x over previous
//
#include <hip/hip_runtime.h>

// LSTM T=1024, B=2048, INPUT=2, H=64 — MFMA recurrence, all-256-CU version.
// R4: 256 blocks x BB=8 batch, 4 waves. MFMA N-columns 8..15 duplicate 0..7
// (B-read/x use bcol&7), so every lane holds valid duplicated gate values:
// lanes bcol<8 activate D-elements {0,1}, bcol>=8 activate {2,3} -> 2 states
// per lane (20 trans ops vs R3's 40). One barrier/step, double-buffered
// h-table, rows 16B-aligned (HSTR=72) so B-frags are single ds_read_b128.
// Numerics identical to R3: bf16 hi/lo W_hh, fresh-rounded bf16 h, fp32 c.

typedef short bf16x8 __attribute__((ext_vector_type(8)));
typedef float f32x4  __attribute__((ext_vector_type(4)));

constexpr int T_STEPS = 1024;
constexpr int BATCH   = 2048;
constexpr int H       = 64;
constexpr int BB      = 8;      // batch per block
constexpr int THREADS = 256;    // 4 waves
constexpr int HSTR    = 72;     // bf16 per batch row: 64 + 8 pad (144B, 16B-aligned)

__device__ __forceinline__ unsigned bf16_rn(float f) {
    unsigned u = __float_as_uint(f);
    u += 0x7fffu + ((u >> 16) & 1u);
    return u >> 16;
}
__device__ __forceinline__ float bf16_f(unsigned h) {
    return __uint_as_float(h << 16);
}
__device__ __forceinline__ float sigm(float v) {
    return __builtin_amdgcn_rcpf(1.0f + __builtin_amdgcn_exp2f(v * -1.44269504f));
}
__device__ __forceinline__ float tanh_(float v) {
    return fmaf(-2.0f, __builtin_amdgcn_rcpf(1.0f + __builtin_amdgcn_exp2f(v * 2.88539008f)), 1.0f);
}

__global__ __launch_bounds__(THREADS, 1) void lstm_mfma8(
    const float* __restrict__ x,      // (T, B, 2)
    const float* __restrict__ W_ih,   // (256, 2)
    const float* __restrict__ W_hh,   // (256, 64)
    const float* __restrict__ b_ih,   // (256)
    const float* __restrict__ b_hh,   // (256)
    const float* __restrict__ W_fc,   // (1, 64)
    const float* __restrict__ b_fc,   // (1)
    float* __restrict__ out)          // (B, 1)
{
    const int tid  = threadIdx.x;
    const int w    = tid >> 6;        // wave 0..3: h-slice [16w, 16w+16)
    const int lane = tid & 63;
    const int bcol = lane & 15;       // MFMA column
    const int grp  = lane >> 4;       // k-group / D-row group
    const int bloc = bcol & 7;        // real batch column (cols 8..15 duplicate)
    const bool elo = (bcol < 8);      // this lane activates e{0,1} vs e{2,3}

    __shared__ __align__(16) unsigned short s_ht[2][BB * HSTR]; // 2 x 1152 B
    __shared__ float s_red[32];

    const int b0 = blockIdx.x * BB;

    // ---- A fragments: gate g tile = W_hh rows [64g+16w, +16), hi/lo bf16 --
    bf16x8 Ahi[4][2], Alo[4][2];
    #pragma unroll
    for (int g = 0; g < 4; ++g) {
        #pragma unroll
        for (int kk = 0; kk < 2; ++kk) {
            const float* src = W_hh + (64 * g + 16 * w + bcol) * H + kk * 32 + grp * 8;
            #pragma unroll
            for (int j = 0; j < 8; ++j) {
                const float v = src[j];
                const unsigned hi = bf16_rn(v);
                const unsigned lo = bf16_rn(v - bf16_f(hi));
                Ahi[g][kk][j] = (short)hi;
                Alo[g][kk][j] = (short)lo;
            }
        }
    }

    // ---- gx constants: D row (gate g) = 64g + 16w + 4grp + e (row-only) ---
    float gb[4][4], c0_[4][4], c1_[4][4];
    #pragma unroll
    for (int g = 0; g < 4; ++g)
        #pragma unroll
        for (int e = 0; e < 4; ++e) {
            const int r = 64 * g + 16 * w + 4 * grp + e;
            gb[g][e]  = b_ih[r] + b_hh[r];
            c0_[g][e] = W_ih[2 * r];
            c1_[g][e] = W_ih[2 * r + 1];
        }

    // ---- per-lane state: rows rbase, rbase+1 of batch b0+bloc -------------
    const int rbase = 16 * w + 4 * grp + (elo ? 0 : 2);
    float cs0 = 0.f, cs1 = 0.f, hv0 = 0.f, hv1 = 0.f;
    const float wfc0 = W_fc[rbase];
    const float wfc1 = W_fc[rbase + 1];

    // zero both h-table buffers (2*8*72 shorts = 576 dwords)
    for (int i = tid; i < 576; i += THREADS)
        reinterpret_cast<unsigned*>(s_ht)[i] = 0;

    // ---- x: depth-2 register prefetch (cols 8..15 duplicate 0..7) ---------
    const float* xb = x + (b0 + bloc) * 2;
    float2 xc  = *reinterpret_cast<const float2*>(xb);
    float2 xn1 = *reinterpret_cast<const float2*>(xb + 1 * BATCH * 2);
    float2 xn2 = *reinterpret_cast<const float2*>(xb + 2 * BATCH * 2);

    __syncthreads();

    // initial B fragments from buf 0 (h = 0); 16B-aligned -> single b128
    bf16x8 Bf[2];
    #pragma unroll
    for (int kk = 0; kk < 2; ++kk)
        Bf[kk] = *reinterpret_cast<const bf16x8*>(
                     &s_ht[0][bloc * HSTR + kk * 32 + grp * 8]);

    #pragma unroll 2
    for (int s = 0; s < T_STEPS; ++s) {
        // acc init = gx (exact fp32)
        f32x4 acc[4];
        #pragma unroll
        for (int g = 0; g < 4; ++g)
            #pragma unroll
            for (int e = 0; e < 4; ++e)
                acc[g][e] = fmaf(c1_[g][e], xc.y, fmaf(c0_[g][e], xc.x, gb[g][e]));

        // recurrent GEMM: 4 gate-chains of 4 dependent MFMAs, interleaved
        #pragma unroll
        for (int kk = 0; kk < 2; ++kk) {
            #pragma unroll
            for (int g = 0; g < 4; ++g)
                acc[g] = __builtin_amdgcn_mfma_f32_16x16x32_bf16(Ahi[g][kk], Bf[kk], acc[g], 0, 0, 0);
            #pragma unroll
            for (int g = 0; g < 4; ++g)
                acc[g] = __builtin_amdgcn_mfma_f32_16x16x32_bf16(Alo[g][kk], Bf[kk], acc[g], 0, 0, 0);
        }

        // select this lane's 2 states (cols duplicated -> both halves valid)
        float p[4], q[4];
        #pragma unroll
        for (int g = 0; g < 4; ++g) {
            p[g] = elo ? acc[g][0] : acc[g][2];
            q[g] = elo ? acc[g][1] : acc[g][3];
        }

        // activations + c/h update, fully in-register (20 trans ops)
        {
            const float i0 = sigm(p[0]), f0 = sigm(p[1]);
            const float g0 = tanh_(p[2]), o0 = sigm(p[3]);
            cs0 = fmaf(f0, cs0, i0 * g0);
            hv0 = o0 * tanh_(cs0);
            const float i1 = sigm(q[0]), f1 = sigm(q[1]);
            const float g1 = tanh_(q[2]), o1 = sigm(q[3]);
            cs1 = fmaf(f1, cs1, i1 * g1);
            hv1 = o1 * tanh_(cs1);
        }

        // pack 2 h -> 1 dword, write to next-parity h-table
        {
            const unsigned pk = bf16_rn(hv0) | (bf16_rn(hv1) << 16);
            *reinterpret_cast<unsigned*>(
                &s_ht[(s + 1) & 1][bloc * HSTR + rbase]) = pk;
        }

        // rotate x prefetch (depth 2)
        xc = xn1; xn1 = xn2;
        const int sn = (s + 3 < T_STEPS) ? s + 3 : T_STEPS - 1;
        xn2 = *reinterpret_cast<const float2*>(xb + sn * BATCH * 2);

        __syncthreads();   // next-parity h-table visible

        // B fragments for next step: single 16B-aligned b128 per kk
        #pragma unroll
        for (int kk = 0; kk < 2; ++kk)
            Bf[kk] = *reinterpret_cast<const bf16x8*>(
                         &s_ht[(s + 1) & 1][bloc * HSTR + kk * 32 + grp * 8]);
    }

    // ---- fused fc epilogue ----------------------------------------------
    float v = fmaf(hv0, wfc0, hv1 * wfc1);
    v += __shfl_xor(v, 8);    // combine e{0,1} and e{2,3} halves (same batch)
    v += __shfl_xor(v, 16);   // combine grp pairs
    v += __shfl_xor(v, 32);
    if (lane < 8) s_red[w * 8 + lane] = v;   // grp==0, elo lanes: one writer
    __syncthreads();
    if (tid < 8) {
        out[b0 + tid] = s_red[tid] + s_red[8 + tid] + s_red[16 + tid]
                      + s_red[24 + tid] + b_fc[0];
    }
}

extern "C" void kernel_launch(void* const* d_in, const int* in_sizes, int n_in,
                              void* d_out, int out_size, void* d_ws, size_t ws_size,
                              hipStream_t stream) {
    const float* x    = (const float*)d_in[0];
    const float* W_ih = (const float*)d_in[1];
    const float* W_hh = (const float*)d_in[2];
    const float* b_ih = (const float*)d_in[3];
    const float* b_hh = (const float*)d_in[4];
    const float* W_fc = (const float*)d_in[5];
    const float* b_fc = (const float*)d_in[6];
    float* out = (float*)d_out;

    dim3 grid(BATCH / BB);   // 256 blocks -> all 256 CUs
    dim3 block(THREADS);     // 4 waves
    lstm_mfma8<<<grid, block, 0, stream>>>(x, W_ih, W_hh, b_ih, b_hh, W_fc, b_fc, out);
}